// Round 5
// baseline (211.409 us; speedup 1.0000x reference)
//
#include <hip/hip_runtime.h>
#include <hip/hip_bf16.h>

#define DDIM 128
#define RDIM 32
#define BLK  256
#define XSTR 136   // xs row stride (u16); 272B
#define HSTR 40    // hs row stride (u16); 80B
#define TPW  10    // tiles (16 nodes) per wave, pipelined

typedef __attribute__((ext_vector_type(8))) short bf16x8;
typedef __attribute__((ext_vector_type(4))) float f32x4;

__device__ __forceinline__ float tanh_fast(float v) {
  float e = __expf(2.f * v);
  return 1.f - 2.f / (e + 1.f);
}
__device__ __forceinline__ float sigmoid_fast(float v) {
  return 1.f / (1.f + __expf(-v));
}
__device__ __forceinline__ unsigned short f2bf(float f) {  // RNE f32->bf16
  unsigned u = __float_as_uint(f);
  u += 0x7fffu + ((u >> 16) & 1u);
  return (unsigned short)(u >> 16);
}
__device__ __forceinline__ float bf2f(unsigned short s) {
  return __uint_as_float(((unsigned)s) << 16);
}
__device__ __forceinline__ unsigned pkbf(float lo, float hi) {  // v_cvt_pk_bf16_f32
  __hip_bfloat162 t2 = __float22bfloat162_rn(make_float2(lo, hi));
  return *reinterpret_cast<unsigned*>(&t2);
}
__device__ __forceinline__ int lower_bound(const int* __restrict__ b, int n, int v) {
  int lo = 0, hi = n;
  while (lo < hi) { int m = (lo + hi) >> 1; if (b[m] < v) lo = m + 1; else hi = m; }
  return lo;
}

// ---------------------------------------------------------------------------
// K0: one-time build of bf16 MFMA weight fragments in ws.
//   w1f: [frag=nt*4+kk][lane][8]  (512 x 8 bf16)
//   w2f: [nt][lane][8]            (512 x 8 bf16)
// B-frag layout (16x16x32): col=l&15, k=(l>>4)*8+j.
// ---------------------------------------------------------------------------
__global__ void k0_prep(const float* __restrict__ w1, const float* __restrict__ w2,
                        unsigned short* __restrict__ w1f, unsigned short* __restrict__ w2f)
{
  const int i  = blockIdx.x * blockDim.x + threadIdx.x;   // 0..1023
  const int l  = i & 63;
  const int lr = l & 15, lq = l >> 4;
  if (i < 512) {
    const int frag = i >> 6;            // nt*4+kk
    const int nt = frag >> 2, kk = frag & 3;
    const int col = nt * 16 + lr;
    const int kb  = kk * 32 + lq * 8;
    bf16x8 v;
    #pragma unroll
    for (int j = 0; j < 8; ++j) v[j] = (short)f2bf(w1[(kb + j) * RDIM + col]);
    *(bf16x8*)&w1f[(size_t)i * 8] = v;
  } else {
    const int frag = (i - 512) >> 6;    // nt
    const int col = frag * 16 + lr;
    const int kb  = lq * 8;
    bf16x8 v;
    #pragma unroll
    for (int j = 0; j < 8; ++j) v[j] = (short)f2bf(w2[(kb + j) * DDIM + col]);
    *(bf16x8*)&w2f[(size_t)(i - 512) * 8] = v;
  }
}

// ---------------------------------------------------------------------------
// K1 (wave-autonomous, pipelined): x2 = x*(1+tanh(relu(x@W1+b1)@W2+b2))
// 4 waves/block, each wave processes TPW tiles of 16 nodes with a register
// prefetch pipeline (issue tile t+1 loads under tile t compute). No barriers.
// Frag layouts (16x16x32 bf16): A row=l&15, k=(l>>4)*8+j;
//                               B col=l&15, k=(l>>4)*8+j;
//                               C/D col=l&15, row=(l>>4)*4+reg.
// ---------------------------------------------------------------------------
__global__ __launch_bounds__(BLK, 3) void k1_mfma(
    const float* __restrict__ x,
    const unsigned short* __restrict__ w1f, const float* __restrict__ b1,
    const unsigned short* __restrict__ w2f, const float* __restrict__ b2,
    unsigned short* __restrict__ x2, int N)
{
  __shared__ unsigned short xs4[4][16 * XSTR];   // 4 x 4352 B
  __shared__ unsigned short hs4[4][16 * HSTR];   // 4 x 1280 B

  const int t  = threadIdx.x;
  const int l  = t & 63;
  const int wv = t >> 6;
  const int lr = l & 15;
  const int lq = l >> 4;
  const long gw  = (long)blockIdx.x * 4 + wv;
  const long tb0 = gw * (TPW * 16);
  if (tb0 >= N) return;
  unsigned short* xs = xs4[wv];
  unsigned short* hs = hs4[wv];

  // ---- weight fragments: coalesced 16B/lane loads (L2-resident) ----
  bf16x8 w1r[2][4], w2r[8];
  #pragma unroll
  for (int nt = 0; nt < 2; ++nt)
    #pragma unroll
    for (int kk = 0; kk < 4; ++kk)
      w1r[nt][kk] = *(const bf16x8*)&w1f[(size_t)((nt * 4 + kk) * 64 + l) * 8];
  #pragma unroll
  for (int nt = 0; nt < 8; ++nt)
    w2r[nt] = *(const bf16x8*)&w2f[(size_t)(nt * 64 + l) * 8];

  float b1v[2], b2v[8];
  b1v[0] = b1[lr]; b1v[1] = b1[16 + lr];
  #pragma unroll
  for (int nt = 0; nt < 8; ++nt) b2v[nt] = b2[nt * 16 + lr];

  const int snode = l >> 5;           // staging: lane covers nodes snode+2j
  const int scol  = (l & 31) * 4;     // 4 floats

  float4 buf[8];
  // ---- prologue: issue tile 0 loads ----
  #pragma unroll
  for (int j = 0; j < 8; ++j) {
    long node = tb0 + snode + 2 * j;
    buf[j] = (node < N) ? *(const float4*)&x[(size_t)node * DDIM + scol]
                        : make_float4(0.f, 0.f, 0.f, 0.f);
  }

  for (int tt = 0; tt < TPW; ++tt) {
    const long tb = tb0 + (long)tt * 16;
    if (tb >= N) break;

    // ---- consume prefetch: convert to bf16, write LDS ----
    #pragma unroll
    for (int j = 0; j < 8; ++j) {
      int node = snode + 2 * j;
      uint2 pk;
      pk.x = pkbf(buf[j].x, buf[j].y);
      pk.y = pkbf(buf[j].z, buf[j].w);
      *(uint2*)&xs[node * XSTR + scol] = pk;
    }

    // ---- issue next tile's loads (fly under this tile's compute) ----
    if (tt + 1 < TPW) {
      const long tbn = tb + 16;
      #pragma unroll
      for (int j = 0; j < 8; ++j) {
        long node = tbn + snode + 2 * j;
        buf[j] = (node < N) ? *(const float4*)&x[(size_t)node * DDIM + scol]
                            : make_float4(0.f, 0.f, 0.f, 0.f);
      }
    }

    // ---- phase B: H = relu(X @ W1 + b1)  (2 Ntiles x 4 Ksteps) ----
    f32x4 hacc[2];
    #pragma unroll
    for (int nt = 0; nt < 2; ++nt)
      #pragma unroll
      for (int c = 0; c < 4; ++c) hacc[nt][c] = b1v[nt];

    #pragma unroll
    for (int kk = 0; kk < 4; ++kk) {
      bf16x8 a = *(const bf16x8*)&xs[lr * XSTR + kk * 32 + lq * 8];
      hacc[0] = __builtin_amdgcn_mfma_f32_16x16x32_bf16(a, w1r[0][kk], hacc[0], 0, 0, 0);
      hacc[1] = __builtin_amdgcn_mfma_f32_16x16x32_bf16(a, w1r[1][kk], hacc[1], 0, 0, 0);
    }

    #pragma unroll
    for (int nt = 0; nt < 2; ++nt)
      #pragma unroll
      for (int c = 0; c < 4; ++c)
        hs[(lq * 4 + c) * HSTR + nt * 16 + lr] = f2bf(fmaxf(hacc[nt][c], 0.f));

    // ---- phase C: A2 = H @ W2 + b2  (8 Ntiles, K=32) ----
    bf16x8 ah = *(const bf16x8*)&hs[lr * HSTR + lq * 8];
    f32x4 cacc[8];
    #pragma unroll
    for (int nt = 0; nt < 8; ++nt)
      #pragma unroll
      for (int c = 0; c < 4; ++c) cacc[nt][c] = b2v[nt];
    #pragma unroll
    for (int nt = 0; nt < 8; ++nt)
      cacc[nt] = __builtin_amdgcn_mfma_f32_16x16x32_bf16(ah, w2r[nt], cacc[nt], 0, 0, 0);

    // ---- gate in LDS: xs <- bf16( x * (1 + tanh(a)) ) ----
    #pragma unroll
    for (int nt = 0; nt < 8; ++nt)
      #pragma unroll
      for (int c = 0; c < 4; ++c) {
        int m   = lq * 4 + c;
        int col = nt * 16 + lr;
        int off = m * XSTR + col;
        float a  = tanh_fast(cacc[nt][c]);
        float xv = bf2f(xs[off]);
        xs[off]  = f2bf(xv * (1.f + a));
      }

    // ---- coalesced bf16 store ----
    #pragma unroll
    for (int k = 0; k < 4; ++k) {
      int idx  = l + k * 64;               // 256 chunks = 16 rows x 16
      int node = idx >> 4, coff = (idx & 15) * 8;
      if (tb + node < N)
        *(bf16x8*)&x2[(size_t)(tb + node) * DDIM + coff] =
            *(const bf16x8*)&xs[node * XSTR + coff];
    }
  }
}

// ---------------------------------------------------------------------------
// K3 (fused): per-graph mean -> tg=tanh(mean@W) in LDS -> coef pass.
// One block per graph; x2 rows hit L2/L3 on the second pass.
// ---------------------------------------------------------------------------
__global__ void k3_graph(
    const unsigned short* __restrict__ x2, const int* __restrict__ batch,
    const float* __restrict__ W, float* __restrict__ out, int N)
{
  __shared__ __align__(16) float part[8][132];
  __shared__ float meanv[DDIM];
  __shared__ float tgs[DDIM];
  __shared__ int bounds[2];
  const int g = blockIdx.x, t = threadIdx.x;
  if (t == 0) bounds[0] = lower_bound(batch, N, g);
  if (t == 1) bounds[1] = lower_bound(batch, N, g + 1);
  __syncthreads();
  const int lo = bounds[0], hi = bounds[1];
  const int q = t & 31, s = t >> 5;

  // ---- phase 1: segment mean ----
  {
    float acc[4] = {0.f, 0.f, 0.f, 0.f};
    for (int n = lo + s; n < hi; n += 8) {
      ushort4 u = *(const ushort4*)&x2[(size_t)n * DDIM + q * 4];
      acc[0] += bf2f(u.x); acc[1] += bf2f(u.y); acc[2] += bf2f(u.z); acc[3] += bf2f(u.w);
    }
    *(float4*)&part[s][q * 4] = make_float4(acc[0], acc[1], acc[2], acc[3]);
  }
  __syncthreads();
  if (t < DDIM) {
    float m = 0.f;
    #pragma unroll
    for (int s2 = 0; s2 < 8; ++s2) m += part[s2][t];
    float invc = (hi > lo) ? 1.f / (float)(hi - lo) : 0.f;
    meanv[t] = m * invc;
  }
  __syncthreads();

  // ---- phase 2: tg = tanh(mean @ W) ----
  if (t < DDIM) {
    float a = 0.f;
    #pragma unroll 8
    for (int k = 0; k < DDIM; ++k) a = fmaf(meanv[k], W[k * DDIM + t], a);
    tgs[t] = tanh_fast(a);
  }
  __syncthreads();

  // ---- phase 3: coefs = sigmoid(x2 . tg); out = sum coefs*x2 ----
  float4 tg4 = *(const float4*)&tgs[q * 4];
  float tga[4] = {tg4.x, tg4.y, tg4.z, tg4.w};
  float acc[4] = {0.f, 0.f, 0.f, 0.f};
  for (int n = lo + s; n < hi; n += 8) {   // 32 lanes of a shuffle group share n
    ushort4 u = *(const ushort4*)&x2[(size_t)n * DDIM + q * 4];
    float xv[4] = {bf2f(u.x), bf2f(u.y), bf2f(u.z), bf2f(u.w)};
    float p = xv[0] * tga[0] + xv[1] * tga[1] + xv[2] * tga[2] + xv[3] * tga[3];
    #pragma unroll
    for (int off = 16; off >= 1; off >>= 1) p += __shfl_xor(p, off, 64);
    float coef = sigmoid_fast(p);
    #pragma unroll
    for (int c = 0; c < 4; ++c) acc[c] = fmaf(coef, xv[c], acc[c]);
  }
  *(float4*)&part[s][q * 4] = make_float4(acc[0], acc[1], acc[2], acc[3]);
  __syncthreads();

  if (t < DDIM) {
    float m = 0.f;
    #pragma unroll
    for (int s2 = 0; s2 < 8; ++s2) m += part[s2][t];
    out[(size_t)g * DDIM + t] = m;
  }
}

// ---------------------------------------------------------------------------
extern "C" void kernel_launch(void* const* d_in, const int* in_sizes, int n_in,
                              void* d_out, int out_size, void* d_ws, size_t ws_size,
                              hipStream_t stream) {
  const float* x     = (const float*)d_in[0];
  const int*   batch = (const int*)d_in[1];
  const float* w1 = (const float*)d_in[3];
  const float* b1 = (const float*)d_in[4];
  const float* w2 = (const float*)d_in[5];
  const float* b2 = (const float*)d_in[6];
  const float* W  = (const float*)d_in[7];
  float* out = (float*)d_out;

  const int N = in_sizes[0] / DDIM;
  const int G = out_size / DDIM;

  // ws layout: [w1f: 4096 bf16][w2f: 4096 bf16][x2: N*128 bf16]
  unsigned short* w1f = (unsigned short*)d_ws;
  unsigned short* w2f = w1f + 4096;
  unsigned short* x2  = w2f + 4096;
  (void)ws_size; (void)n_in;

  hipLaunchKernelGGL(k0_prep, dim3(4), dim3(BLK), 0, stream, w1, w2, w1f, w2f);
  const int nodes_per_block = 64 * TPW;   // 4 waves x 16 nodes x TPW tiles
  const int grid1 = (N + nodes_per_block - 1) / nodes_per_block;
  hipLaunchKernelGGL(k1_mfma, dim3(grid1), dim3(BLK), 0, stream, x, w1f, b1, w2f, b2, x2, N);
  hipLaunchKernelGGL(k3_graph, dim3(G), dim3(BLK), 0, stream, x2, batch, W, out, N);
}

// Round 6
// 164.082 us; speedup vs baseline: 1.2884x; 1.2884x over previous
//
#include <hip/hip_runtime.h>
#include <hip/hip_bf16.h>

#define DDIM 128
#define RDIM 32
#define BLK  256
#define HSTR 40    // hs row stride in u16 (80 B)

typedef __attribute__((ext_vector_type(8))) short bf16x8;
typedef __attribute__((ext_vector_type(4))) float f32x4;

__device__ __forceinline__ float tanh_fast(float v) {
  float e = __expf(2.f * v);
  return 1.f - 2.f / (e + 1.f);
}
__device__ __forceinline__ float sigmoid_fast(float v) {
  return 1.f / (1.f + __expf(-v));
}
__device__ __forceinline__ unsigned short f2bf(float f) {  // RNE f32->bf16
  unsigned u = __float_as_uint(f);
  u += 0x7fffu + ((u >> 16) & 1u);
  return (unsigned short)(u >> 16);
}
__device__ __forceinline__ float bf2f(unsigned short s) {
  return __uint_as_float(((unsigned)s) << 16);
}
__device__ __forceinline__ unsigned pkbf(float lo, float hi) {  // v_cvt_pk_bf16_f32
  __hip_bfloat162 t2 = __float22bfloat162_rn(make_float2(lo, hi));
  return *reinterpret_cast<unsigned*>(&t2);
}
__device__ __forceinline__ int lower_bound(const int* __restrict__ b, int n, int v) {
  int lo = 0, hi = n;
  while (lo < hi) { int m = (lo + hi) >> 1; if (b[m] < v) lo = m + 1; else hi = m; }
  return lo;
}

// ---------------------------------------------------------------------------
// K0: build bf16 A-fragments of W1^T and W2^T (for transposed-GEMM K1).
//   w1tf[frag=mt2*4+kk][lane][8] : W1^T[r=mt2*16+lr][d=kk*32+q*8+j]
//   w2tf[mt][lane][8]            : W2^T[d=mt*16+lr][r=q*8+j]
// A-frag layout (16x16x32): row=l&15, k=(l>>4)*8+j.
// ---------------------------------------------------------------------------
__global__ void k0_prep(const float* __restrict__ w1, const float* __restrict__ w2,
                        unsigned short* __restrict__ w1tf, unsigned short* __restrict__ w2tf)
{
  const int i  = blockIdx.x * blockDim.x + threadIdx.x;   // 0..1023
  const int l  = i & 63;
  const int lr = l & 15, q = l >> 4;
  if (i < 512) {
    const int frag = i >> 6;             // mt2*4+kk
    const int mt2 = frag >> 2, kk = frag & 3;
    bf16x8 v;
    #pragma unroll
    for (int j = 0; j < 8; ++j)
      v[j] = (short)f2bf(w1[(size_t)(kk * 32 + q * 8 + j) * RDIM + mt2 * 16 + lr]);
    *(bf16x8*)&w1tf[(size_t)i * 8] = v;
  } else {
    const int mt = (i - 512) >> 6;
    bf16x8 v;
    #pragma unroll
    for (int j = 0; j < 8; ++j)
      v[j] = (short)f2bf(w2[(size_t)(q * 8 + j) * DDIM + mt * 16 + lr]);
    *(bf16x8*)&w2tf[(size_t)(i - 512) * 8] = v;
  }
}

// ---------------------------------------------------------------------------
// K1: x2 = x*(1+tanh(relu(x@W1+b1)@W2+b2)) -> bf16, transposed-MFMA form.
// H^T = W1^T @ X^T ; A2^T = W2^T @ H^T. Every C/D has col=node=l&15, so the
// gate runs fully in registers; x never staged in LDS. One 16-node tile/wave.
// ---------------------------------------------------------------------------
__global__ __launch_bounds__(BLK, 3) void k1_mfma(
    const float* __restrict__ x,
    const unsigned short* __restrict__ w1tf, const float* __restrict__ b1,
    const unsigned short* __restrict__ w2tf, const float* __restrict__ b2,
    unsigned short* __restrict__ x2, int N)
{
  __shared__ unsigned short w1t[512 * 8];        // 8 KB
  __shared__ unsigned short w2t[512 * 8];        // 8 KB
  __shared__ unsigned short hs4[4][16 * HSTR];   // 4 x 1280 B

  const int t  = threadIdx.x;
  const int l  = t & 63;
  const int wv = t >> 6;
  const int lr = l & 15;
  const int q  = l >> 4;

  // ---- stage weight fragments to LDS (block-shared), once ----
  for (int i = t; i < 512; i += BLK) {
    ((bf16x8*)w1t)[i] = ((const bf16x8*)w1tf)[i];
    ((bf16x8*)w2t)[i] = ((const bf16x8*)w2tf)[i];
  }
  __syncthreads();

  const int node0 = (blockIdx.x * 4 + wv) * 16;
  if (node0 >= N) return;
  const int row  = node0 + lr;
  const int rowc = min(row, N - 1);               // clamp (tail safety)
  const float* xrow = x + (size_t)rowc * DDIM;

  // ---- gate-copy loads: x[row][mt*16+q*4 .. +4)  (perfect coalescing) ----
  float4 xg[8];
  #pragma unroll
  for (int mt = 0; mt < 8; ++mt)
    xg[mt] = *(const float4*)(xrow + mt * 16 + q * 4);

  // ---- B-frags of X^T: x[row][kk*32+q*8 .. +8) -> bf16x8 ----
  bf16x8 xf[4];
  #pragma unroll
  for (int kk = 0; kk < 4; ++kk) {
    float4 a = *(const float4*)(xrow + kk * 32 + q * 8);
    float4 b = *(const float4*)(xrow + kk * 32 + q * 8 + 4);
    uint4 u;
    u.x = pkbf(a.x, a.y); u.y = pkbf(a.z, a.w);
    u.z = pkbf(b.x, b.y); u.w = pkbf(b.z, b.w);
    xf[kk] = *(bf16x8*)&u;
  }

  // ---- phase B: H^T = W1^T @ X^T + b1 (2 Mtiles x 4 Ksteps) ----
  f32x4 hacc[2];
  #pragma unroll
  for (int mt2 = 0; mt2 < 2; ++mt2) {
    float4 bv = *(const float4*)(b1 + mt2 * 16 + q * 4);
    hacc[mt2][0] = bv.x; hacc[mt2][1] = bv.y; hacc[mt2][2] = bv.z; hacc[mt2][3] = bv.w;
  }
  #pragma unroll
  for (int kk = 0; kk < 4; ++kk) {
    #pragma unroll
    for (int mt2 = 0; mt2 < 2; ++mt2) {
      bf16x8 wfr = *(const bf16x8*)&w1t[(size_t)((mt2 * 4 + kk) * 64 + l) * 8];
      hacc[mt2] = __builtin_amdgcn_mfma_f32_16x16x32_bf16(wfr, xf[kk], hacc[mt2], 0, 0, 0);
    }
  }

  // ---- relu + pack -> hs[node][r] (2 x ds_write_b64), read H^T B-frag ----
  unsigned short* hs = hs4[wv];
  #pragma unroll
  for (int mt2 = 0; mt2 < 2; ++mt2) {
    float h0 = fmaxf(hacc[mt2][0], 0.f), h1 = fmaxf(hacc[mt2][1], 0.f);
    float h2 = fmaxf(hacc[mt2][2], 0.f), h3 = fmaxf(hacc[mt2][3], 0.f);
    uint2 p; p.x = pkbf(h0, h1); p.y = pkbf(h2, h3);
    *(uint2*)&hs[lr * HSTR + mt2 * 16 + q * 4] = p;
  }
  bf16x8 ah = *(const bf16x8*)&hs[lr * HSTR + q * 8];   // col=node, k=r

  // ---- phase C: A2^T = W2^T @ H^T (8 Mtiles, K=32) ----
  f32x4 cacc[8];
  #pragma unroll
  for (int mt = 0; mt < 8; ++mt)
    #pragma unroll
    for (int c = 0; c < 4; ++c) cacc[mt][c] = 0.f;
  #pragma unroll
  for (int mt = 0; mt < 8; ++mt) {
    bf16x8 wfr = *(const bf16x8*)&w2t[(size_t)(mt * 64 + l) * 8];
    cacc[mt] = __builtin_amdgcn_mfma_f32_16x16x32_bf16(wfr, ah, cacc[mt], 0, 0, 0);
  }

  // ---- gate in registers + packed store ----
  if (row < N) {
    unsigned short* orow = x2 + (size_t)row * DDIM;
    #pragma unroll
    for (int mt = 0; mt < 8; ++mt) {
      float4 bv = *(const float4*)(b2 + mt * 16 + q * 4);
      float y0 = xg[mt].x * (1.f + tanh_fast(cacc[mt][0] + bv.x));
      float y1 = xg[mt].y * (1.f + tanh_fast(cacc[mt][1] + bv.y));
      float y2 = xg[mt].z * (1.f + tanh_fast(cacc[mt][2] + bv.z));
      float y3 = xg[mt].w * (1.f + tanh_fast(cacc[mt][3] + bv.w));
      uint2 p; p.x = pkbf(y0, y1); p.y = pkbf(y2, y3);
      *(uint2*)&orow[mt * 16 + q * 4] = p;
    }
  }
}

// ---------------------------------------------------------------------------
// K3 (fused): per-graph mean -> tg=tanh(mean@W) in LDS -> coef pass.
// One block per graph; x2 rows hit L2/L3 on the second pass.
// ---------------------------------------------------------------------------
__global__ void k3_graph(
    const unsigned short* __restrict__ x2, const int* __restrict__ batch,
    const float* __restrict__ W, float* __restrict__ out, int N)
{
  __shared__ __align__(16) float part[8][132];
  __shared__ float meanv[DDIM];
  __shared__ float tgs[DDIM];
  __shared__ int bounds[2];
  const int g = blockIdx.x, t = threadIdx.x;
  if (t == 0) bounds[0] = lower_bound(batch, N, g);
  if (t == 1) bounds[1] = lower_bound(batch, N, g + 1);
  __syncthreads();
  const int lo = bounds[0], hi = bounds[1];
  const int q = t & 31, s = t >> 5;

  // ---- phase 1: segment mean ----
  {
    float acc[4] = {0.f, 0.f, 0.f, 0.f};
    for (int n = lo + s; n < hi; n += 8) {
      ushort4 u = *(const ushort4*)&x2[(size_t)n * DDIM + q * 4];
      acc[0] += bf2f(u.x); acc[1] += bf2f(u.y); acc[2] += bf2f(u.z); acc[3] += bf2f(u.w);
    }
    *(float4*)&part[s][q * 4] = make_float4(acc[0], acc[1], acc[2], acc[3]);
  }
  __syncthreads();
  if (t < DDIM) {
    float m = 0.f;
    #pragma unroll
    for (int s2 = 0; s2 < 8; ++s2) m += part[s2][t];
    float invc = (hi > lo) ? 1.f / (float)(hi - lo) : 0.f;
    meanv[t] = m * invc;
  }
  __syncthreads();

  // ---- phase 2: tg = tanh(mean @ W) ----
  if (t < DDIM) {
    float a = 0.f;
    #pragma unroll 8
    for (int k = 0; k < DDIM; ++k) a = fmaf(meanv[k], W[k * DDIM + t], a);
    tgs[t] = tanh_fast(a);
  }
  __syncthreads();

  // ---- phase 3: coefs = sigmoid(x2 . tg); out = sum coefs*x2 ----
  float4 tg4 = *(const float4*)&tgs[q * 4];
  float tga[4] = {tg4.x, tg4.y, tg4.z, tg4.w};
  float acc[4] = {0.f, 0.f, 0.f, 0.f};
  for (int n = lo + s; n < hi; n += 8) {   // 32 lanes of a shuffle group share n
    ushort4 u = *(const ushort4*)&x2[(size_t)n * DDIM + q * 4];
    float xv[4] = {bf2f(u.x), bf2f(u.y), bf2f(u.z), bf2f(u.w)};
    float p = xv[0] * tga[0] + xv[1] * tga[1] + xv[2] * tga[2] + xv[3] * tga[3];
    #pragma unroll
    for (int off = 16; off >= 1; off >>= 1) p += __shfl_xor(p, off, 64);
    float coef = sigmoid_fast(p);
    #pragma unroll
    for (int c = 0; c < 4; ++c) acc[c] = fmaf(coef, xv[c], acc[c]);
  }
  *(float4*)&part[s][q * 4] = make_float4(acc[0], acc[1], acc[2], acc[3]);
  __syncthreads();

  if (t < DDIM) {
    float m = 0.f;
    #pragma unroll
    for (int s2 = 0; s2 < 8; ++s2) m += part[s2][t];
    out[(size_t)g * DDIM + t] = m;
  }
}

// ---------------------------------------------------------------------------
extern "C" void kernel_launch(void* const* d_in, const int* in_sizes, int n_in,
                              void* d_out, int out_size, void* d_ws, size_t ws_size,
                              hipStream_t stream) {
  const float* x     = (const float*)d_in[0];
  const int*   batch = (const int*)d_in[1];
  const float* w1 = (const float*)d_in[3];
  const float* b1 = (const float*)d_in[4];
  const float* w2 = (const float*)d_in[5];
  const float* b2 = (const float*)d_in[6];
  const float* W  = (const float*)d_in[7];
  float* out = (float*)d_out;

  const int N = in_sizes[0] / DDIM;
  const int G = out_size / DDIM;

  // ws layout: [w1tf: 4096 bf16][w2tf: 4096 bf16][x2: N*128 bf16]
  unsigned short* w1tf = (unsigned short*)d_ws;
  unsigned short* w2tf = w1tf + 4096;
  unsigned short* x2   = w2tf + 4096;
  (void)ws_size; (void)n_in;

  hipLaunchKernelGGL(k0_prep, dim3(4), dim3(BLK), 0, stream, w1, w2, w1tf, w2tf);
  const int grid1 = (N + 63) / 64;          // 64 nodes/block (4 waves x 16)
  hipLaunchKernelGGL(k1_mfma, dim3(grid1), dim3(BLK), 0, stream, x, w1tf, b1, w2tf, b2, x2, N);
  hipLaunchKernelGGL(k3_graph, dim3(G), dim3(BLK), 0, stream, x2, batch, W, out, N);
}